// Round 2
// baseline (622.631 us; speedup 1.0000x reference)
//
#include <hip/hip_runtime.h>
#include <math.h>

#define NN 50000
#define EE 1000000

// ---------------- kernel 1: x_l = x@Wl+bl, x_r = x@Wr+br ----------------
__global__ __launch_bounds__(256) void lin_kernel(
    const float* __restrict__ x,
    const float* __restrict__ Wl, const float* __restrict__ bl,
    const float* __restrict__ Wr, const float* __restrict__ br,
    float* __restrict__ xl, float* __restrict__ xr)
{
  __shared__ float xs[32][128];
  const int tid = threadIdx.x;
  const int r0 = blockIdx.x * 32;

  // stage 32x128 x-tile (1024 float4 loads)
  for (int i = tid; i < 32 * 32; i += 256) {
    int row = i >> 5, c4 = (i & 31) * 4;
    float4 v = make_float4(0.f, 0.f, 0.f, 0.f);
    if (r0 + row < NN) v = *(const float4*)&x[(size_t)(r0 + row) * 128 + c4];
    *(float4*)&xs[row][c4] = v;
  }
  __syncthreads();

  const int jg = (tid & 31) * 4;   // 4 output cols
  const int rg = (tid >> 5) * 4;   // 4 rows

  float accl[4][4], accr[4][4];
  #pragma unroll
  for (int r = 0; r < 4; ++r)
    #pragma unroll
    for (int c = 0; c < 4; ++c) { accl[r][c] = 0.f; accr[r][c] = 0.f; }

  for (int k4 = 0; k4 < 128; k4 += 4) {
    float4 xv[4];
    #pragma unroll
    for (int r = 0; r < 4; ++r) xv[r] = *(const float4*)&xs[rg + r][k4];
    #pragma unroll
    for (int kk = 0; kk < 4; ++kk) {
      float4 wl4 = *(const float4*)&Wl[(size_t)(k4 + kk) * 128 + jg];
      float4 wr4 = *(const float4*)&Wr[(size_t)(k4 + kk) * 128 + jg];
      #pragma unroll
      for (int r = 0; r < 4; ++r) {
        float xk = (kk == 0) ? xv[r].x : (kk == 1) ? xv[r].y : (kk == 2) ? xv[r].z : xv[r].w;
        accl[r][0] = fmaf(xk, wl4.x, accl[r][0]);
        accl[r][1] = fmaf(xk, wl4.y, accl[r][1]);
        accl[r][2] = fmaf(xk, wl4.z, accl[r][2]);
        accl[r][3] = fmaf(xk, wl4.w, accl[r][3]);
        accr[r][0] = fmaf(xk, wr4.x, accr[r][0]);
        accr[r][1] = fmaf(xk, wr4.y, accr[r][1]);
        accr[r][2] = fmaf(xk, wr4.z, accr[r][2]);
        accr[r][3] = fmaf(xk, wr4.w, accr[r][3]);
      }
    }
  }

  float4 bl4 = *(const float4*)&bl[jg];
  float4 br4 = *(const float4*)&br[jg];
  #pragma unroll
  for (int r = 0; r < 4; ++r) {
    int row = r0 + rg + r;
    if (row < NN) {
      float4 ol = make_float4(accl[r][0] + bl4.x, accl[r][1] + bl4.y,
                              accl[r][2] + bl4.z, accl[r][3] + bl4.w);
      float4 orr = make_float4(accr[r][0] + br4.x, accr[r][1] + br4.y,
                               accr[r][2] + br4.z, accr[r][3] + br4.w);
      *(float4*)&xl[(size_t)row * 128 + jg] = ol;
      *(float4*)&xr[(size_t)row * 128 + jg] = orr;
    }
  }
}

// ---------------- CSR build ----------------
__global__ void count_kernel(const int* __restrict__ dst, int* __restrict__ counts)
{
  int i = blockIdx.x * blockDim.x + threadIdx.x;
  int stride = gridDim.x * blockDim.x;
  for (; i < EE; i += stride) atomicAdd(&counts[dst[i]], 1);
}

__global__ __launch_bounds__(1024) void scan_kernel(const int* __restrict__ counts,
                                                    int* __restrict__ row_ptr)
{
  __shared__ int s[1024];
  const int t = threadIdx.x;
  const int CH = (NN + 1023) / 1024;   // 49
  const int base = t * CH;
  int sum = 0;
  for (int j = 0; j < CH; ++j) {
    int idx = base + j;
    if (idx < NN) sum += counts[idx];
  }
  s[t] = sum;
  __syncthreads();
  for (int ofs = 1; ofs < 1024; ofs <<= 1) {
    int v = (t >= ofs) ? s[t - ofs] : 0;
    __syncthreads();
    s[t] += v;
    __syncthreads();
  }
  int run = s[t] - sum;  // exclusive prefix of this thread's chunk
  for (int j = 0; j < CH; ++j) {
    int idx = base + j;
    if (idx < NN) { row_ptr[idx] = run; run += counts[idx]; }
  }
  if (t == 1023) row_ptr[NN] = s[1023];
}

__global__ void fill_kernel(const int* __restrict__ src, const int* __restrict__ dst,
                            int* __restrict__ cur, const int* __restrict__ row_ptr,
                            int2* __restrict__ csr)
{
  int i = blockIdx.x * blockDim.x + threadIdx.x;
  int stride = gridDim.x * blockDim.x;
  for (; i < EE; i += stride) {
    int d = dst[i];
    int pos = row_ptr[d] + atomicAdd(&cur[d], 1);
    csr[pos] = make_int2(src[i], i);
  }
}

// ---------------- fused per-node kernel ----------------
template<int CTRL>
__device__ __forceinline__ float dpp_add(float v)
{
  int y = __builtin_amdgcn_update_dpp(0, __float_as_int(v), CTRL, 0xF, 0xF, true);
  return v + __int_as_float(y);
}

__global__ __launch_bounds__(128) void node_kernel(
    const float* __restrict__ x,
    const float* __restrict__ edge_attr,
    const float* __restrict__ We,
    const float* __restrict__ att,
    const float* __restrict__ bias_out,
    const float* __restrict__ gamma,
    const float* __restrict__ beta,
    const float* __restrict__ xl,
    const float* __restrict__ xr,
    const int* __restrict__ row_ptr,
    const int2* __restrict__ csr,
    float* __restrict__ out)
{
  const int n = blockIdx.x;
  const int tid = threadIdx.x;   // channel hc = h*32 + c

  float We_r[16];
  #pragma unroll
  for (int k = 0; k < 16; ++k) We_r[k] = We[k * 128 + tid];
  const float att_v = att[tid];
  const float xr_v = xr[(size_t)n * 128 + tid];

  float m_run = -INFINITY, s_run = 0.f, acc = 0.f;
  const int i0 = __builtin_amdgcn_readfirstlane(row_ptr[n]);
  const int i1 = __builtin_amdgcn_readfirstlane(row_ptr[n + 1]);

  for (int i = i0; i < i1; ++i) {
    int2 se = csr[i];
    int s   = __builtin_amdgcn_readfirstlane(se.x);
    int eid = __builtin_amdgcn_readfirstlane(se.y);

    float xl_v = xl[(size_t)s * 128 + tid];

    const float* __restrict__ ea = edge_attr + (size_t)eid * 16;
    float ev = 0.f;
    #pragma unroll
    for (int k = 0; k < 16; ++k) ev = fmaf(ea[k], We_r[k], ev);

    float sm = xl_v + xr_v + ev;
    sm = fmaxf(sm, 0.2f * sm);          // leaky_relu, slope 0.2
    float part = sm * att_v;

    // sum over the 32 lanes of this head: quad xor1, xor2, 8-mirror, 16-mirror, xor16
    part = dpp_add<0xB1>(part);         // quad_perm [1,0,3,2]
    part = dpp_add<0x4E>(part);         // quad_perm [2,3,0,1]
    part = dpp_add<0x141>(part);        // row_half_mirror
    part = dpp_add<0x140>(part);        // row_mirror
    {
      int y = __builtin_amdgcn_ds_swizzle(__float_as_int(part), 0x401F); // xor 16
      part += __int_as_float(y);
    }
    const float alpha = part;

    // online softmax update
    const float nm = fmaxf(m_run, alpha);
    const float sc = __expf(m_run - nm);
    const float p  = __expf(alpha - nm);
    s_run = fmaf(s_run, sc, p);
    acc   = acc * sc + p * xl_v;
    m_run = nm;
  }

  float o  = acc / (s_run + 1e-16f) + bias_out[tid];
  float hv = o > 0.f ? o : expm1f(o);       // ELU
  float v  = hv + x[(size_t)n * 128 + tid]; // residual

  // LayerNorm over 128 channels (2 waves)
  float s1 = v, s2 = v * v;
  #pragma unroll
  for (int m = 1; m < 64; m <<= 1) {
    s1 += __shfl_xor(s1, m, 64);
    s2 += __shfl_xor(s2, m, 64);
  }
  __shared__ float red[4];
  if ((tid & 63) == 0) { red[(tid >> 6) * 2] = s1; red[(tid >> 6) * 2 + 1] = s2; }
  __syncthreads();
  float S  = red[0] + red[2];
  float SQ = red[1] + red[3];
  float mean = S * (1.f / 128.f);
  float var  = SQ * (1.f / 128.f) - mean * mean;
  out[(size_t)n * 128 + tid] =
      (v - mean) * rsqrtf(var + 1e-5f) * gamma[tid] + beta[tid];
}

// ---------------- launch ----------------
extern "C" void kernel_launch(void* const* d_in, const int* in_sizes, int n_in,
                              void* d_out, int out_size, void* d_ws, size_t ws_size,
                              hipStream_t stream)
{
  const float* x         = (const float*)d_in[0];
  const int*   edge_idx  = (const int*)d_in[1];
  const float* edge_attr = (const float*)d_in[2];
  const float* Wl        = (const float*)d_in[3];
  const float* bl        = (const float*)d_in[4];
  const float* Wr        = (const float*)d_in[5];
  const float* br        = (const float*)d_in[6];
  const float* We        = (const float*)d_in[7];
  const float* att       = (const float*)d_in[8];
  const float* bias_out  = (const float*)d_in[9];
  const float* gamma     = (const float*)d_in[10];
  const float* beta      = (const float*)d_in[11];
  float* out = (float*)d_out;

  const int* src = edge_idx;        // edge_index[0]
  const int* dst = edge_idx + EE;   // edge_index[1]

  char* ws = (char*)d_ws;
  float* xl = (float*)ws;            ws += (size_t)NN * 128 * 4;   // 25.6 MB
  float* xr = (float*)ws;            ws += (size_t)NN * 128 * 4;   // 25.6 MB
  int* counts = (int*)ws;            ws += (size_t)NN * 4;
  int* cur    = (int*)ws;            ws += (size_t)NN * 4;
  int* row_ptr = (int*)ws;           ws += (size_t)(NN + 16) * 4;  // padded for alignment
  int2* csr = (int2*)ws;                                           // 8 MB

  // zero counts + cur (contiguous)
  hipMemsetAsync(counts, 0, (size_t)NN * 2 * 4, stream);

  lin_kernel<<<(NN + 31) / 32, 256, 0, stream>>>(x, Wl, bl, Wr, br, xl, xr);
  count_kernel<<<1024, 256, 0, stream>>>(dst, counts);
  scan_kernel<<<1, 1024, 0, stream>>>(counts, row_ptr);
  fill_kernel<<<1024, 256, 0, stream>>>(src, dst, cur, row_ptr, csr);
  node_kernel<<<NN, 128, 0, stream>>>(x, edge_attr, We, att, bias_out, gamma, beta,
                                      xl, xr, row_ptr, csr, out);
}

// Round 3
// 581.001 us; speedup vs baseline: 1.0717x; 1.0717x over previous
//
#include <hip/hip_runtime.h>
#include <math.h>

#define NN 50000
#define EE 1000000
#define LIN_BLOCKS ((NN + 31) / 32)          // 1563
#define CNT_THREADS ((EE / 4))               // 250000 int4 units
#define CNT_BLOCKS ((CNT_THREADS + 255) / 256) // 977

// ---------------- fused kernel 1: {x@Wl+bl, x@Wr+br} grid-fused with degree count ----------------
__global__ __launch_bounds__(256) void lin_count_kernel(
    const float* __restrict__ x,
    const float* __restrict__ Wl, const float* __restrict__ bl,
    const float* __restrict__ Wr, const float* __restrict__ br,
    float* __restrict__ xl, float* __restrict__ xr,
    const int* __restrict__ dst, int* __restrict__ counts)
{
  const int tid = threadIdx.x;

  if (blockIdx.x >= LIN_BLOCKS) {
    // ---- count part: int4-vectorized histogram of dst ----
    int t = (blockIdx.x - LIN_BLOCKS) * 256 + tid;
    if (t < CNT_THREADS) {
      int4 d4 = ((const int4*)dst)[t];
      atomicAdd(&counts[d4.x], 1);
      atomicAdd(&counts[d4.y], 1);
      atomicAdd(&counts[d4.z], 1);
      atomicAdd(&counts[d4.w], 1);
    }
    return;
  }

  // ---- lin part ----
  __shared__ float xs[32][128];
  const int r0 = blockIdx.x * 32;

  for (int i = tid; i < 32 * 32; i += 256) {
    int row = i >> 5, c4 = (i & 31) * 4;
    float4 v = make_float4(0.f, 0.f, 0.f, 0.f);
    if (r0 + row < NN) v = *(const float4*)&x[(size_t)(r0 + row) * 128 + c4];
    *(float4*)&xs[row][c4] = v;
  }
  __syncthreads();

  const int jg = (tid & 31) * 4;
  const int rg = (tid >> 5) * 4;

  float accl[4][4], accr[4][4];
  #pragma unroll
  for (int r = 0; r < 4; ++r)
    #pragma unroll
    for (int c = 0; c < 4; ++c) { accl[r][c] = 0.f; accr[r][c] = 0.f; }

  for (int k4 = 0; k4 < 128; k4 += 4) {
    float4 xv[4];
    #pragma unroll
    for (int r = 0; r < 4; ++r) xv[r] = *(const float4*)&xs[rg + r][k4];
    #pragma unroll
    for (int kk = 0; kk < 4; ++kk) {
      float4 wl4 = *(const float4*)&Wl[(size_t)(k4 + kk) * 128 + jg];
      float4 wr4 = *(const float4*)&Wr[(size_t)(k4 + kk) * 128 + jg];
      #pragma unroll
      for (int r = 0; r < 4; ++r) {
        float xk = (kk == 0) ? xv[r].x : (kk == 1) ? xv[r].y : (kk == 2) ? xv[r].z : xv[r].w;
        accl[r][0] = fmaf(xk, wl4.x, accl[r][0]);
        accl[r][1] = fmaf(xk, wl4.y, accl[r][1]);
        accl[r][2] = fmaf(xk, wl4.z, accl[r][2]);
        accl[r][3] = fmaf(xk, wl4.w, accl[r][3]);
        accr[r][0] = fmaf(xk, wr4.x, accr[r][0]);
        accr[r][1] = fmaf(xk, wr4.y, accr[r][1]);
        accr[r][2] = fmaf(xk, wr4.z, accr[r][2]);
        accr[r][3] = fmaf(xk, wr4.w, accr[r][3]);
      }
    }
  }

  float4 bl4 = *(const float4*)&bl[jg];
  float4 br4 = *(const float4*)&br[jg];
  #pragma unroll
  for (int r = 0; r < 4; ++r) {
    int row = r0 + rg + r;
    if (row < NN) {
      float4 ol = make_float4(accl[r][0] + bl4.x, accl[r][1] + bl4.y,
                              accl[r][2] + bl4.z, accl[r][3] + bl4.w);
      float4 orr = make_float4(accr[r][0] + br4.x, accr[r][1] + br4.y,
                               accr[r][2] + br4.z, accr[r][3] + br4.w);
      *(float4*)&xl[(size_t)row * 128 + jg] = ol;
      *(float4*)&xr[(size_t)row * 128 + jg] = orr;
    }
  }
}

// ---------------- scan: row_ptr (exclusive) + cursor copy ----------------
__global__ __launch_bounds__(1024) void scan_kernel(const int* __restrict__ counts,
                                                    int* __restrict__ row_ptr,
                                                    int* __restrict__ cursor)
{
  __shared__ int s[1024];
  const int t = threadIdx.x;
  const int CH = (NN + 1023) / 1024;   // 49
  const int base = t * CH;
  int sum = 0;
  for (int j = 0; j < CH; ++j) {
    int idx = base + j;
    if (idx < NN) sum += counts[idx];
  }
  s[t] = sum;
  __syncthreads();
  for (int ofs = 1; ofs < 1024; ofs <<= 1) {
    int v = (t >= ofs) ? s[t - ofs] : 0;
    __syncthreads();
    s[t] += v;
    __syncthreads();
  }
  int run = s[t] - sum;
  for (int j = 0; j < CH; ++j) {
    int idx = base + j;
    if (idx < NN) { row_ptr[idx] = run; cursor[idx] = run; run += counts[idx]; }
  }
  if (t == 1023) row_ptr[NN] = s[1023];
}

// ---------------- fill: int4-vectorized CSR fill ----------------
__global__ __launch_bounds__(256) void fill_kernel(const int* __restrict__ src,
                                                   const int* __restrict__ dst,
                                                   int* __restrict__ cursor,
                                                   int2* __restrict__ csr)
{
  int t = blockIdx.x * 256 + threadIdx.x;
  if (t >= CNT_THREADS) return;
  int4 s4 = ((const int4*)src)[t];
  int4 d4 = ((const int4*)dst)[t];
  int e0 = t * 4;
  int p;
  p = atomicAdd(&cursor[d4.x], 1); csr[p] = make_int2(s4.x, e0 + 0);
  p = atomicAdd(&cursor[d4.y], 1); csr[p] = make_int2(s4.y, e0 + 1);
  p = atomicAdd(&cursor[d4.z], 1); csr[p] = make_int2(s4.z, e0 + 2);
  p = atomicAdd(&cursor[d4.w], 1); csr[p] = make_int2(s4.w, e0 + 3);
}

// ---------------- fused per-node kernel: 1 wave per node, 2 channels/lane ----------------
template<int CTRL>
__device__ __forceinline__ float dpp_add(float v)
{
  int y = __builtin_amdgcn_update_dpp(0, __float_as_int(v), CTRL, 0xF, 0xF, true);
  return v + __int_as_float(y);
}

__device__ __forceinline__ float head_reduce32(float v)
{
  v = dpp_add<0xB1>(v);    // quad_perm [1,0,3,2]  (xor 1)
  v = dpp_add<0x4E>(v);    // quad_perm [2,3,0,1]  (xor 2)
  v = dpp_add<0x141>(v);   // row_half_mirror      (completes 8-group)
  v = dpp_add<0x140>(v);   // row_mirror           (completes 16-group)
  int y = __builtin_amdgcn_ds_swizzle(__float_as_int(v), 0x401F); // xor 16 within 32
  return v + __int_as_float(y);
}

__global__ __launch_bounds__(256) void node_kernel(
    const float* __restrict__ x,
    const float* __restrict__ edge_attr,
    const float* __restrict__ We,
    const float* __restrict__ att,
    const float* __restrict__ bias_out,
    const float* __restrict__ gamma,
    const float* __restrict__ beta,
    const float* __restrict__ xl,
    const float* __restrict__ xr,
    const int* __restrict__ row_ptr,
    const int2* __restrict__ csr,
    float* __restrict__ out)
{
  const int lane = threadIdx.x & 63;
  const int n = blockIdx.x * 4 + (threadIdx.x >> 6);   // 12500*4 = 50000 exactly
  const int c0 = lane;          // head lane>>5 (0/1)
  const int c1 = lane + 64;     // head 2 + lane>>5 (2/3)

  // per-lane constants
  float We0[16], We1[16];
  #pragma unroll
  for (int k = 0; k < 16; ++k) { We0[k] = We[k * 128 + c0]; We1[k] = We[k * 128 + c1]; }
  const float att0 = att[c0], att1 = att[c1];
  const float xr0 = xr[(size_t)n * 128 + c0];
  const float xr1 = xr[(size_t)n * 128 + c1];

  const int i0 = __builtin_amdgcn_readfirstlane(row_ptr[n]);
  const int i1 = __builtin_amdgcn_readfirstlane(row_ptr[n + 1]);

  float S0 = 0.f, S1 = 0.f, A0 = 0.f, A1 = 0.f;

  for (int i = i0; i < i1; ++i) {
    int2 se = csr[i];
    int s   = __builtin_amdgcn_readfirstlane(se.x);
    int eid = __builtin_amdgcn_readfirstlane(se.y);

    const float* __restrict__ xlp = xl + (size_t)s * 128;
    float v0 = xlp[c0];
    float v1 = xlp[c1];

    const float* __restrict__ ea = edge_attr + (size_t)eid * 16;
    float e0 = xr0, e1 = xr1;          // fold +xr into the FMA accumulator init
    #pragma unroll
    for (int k = 0; k < 16; ++k) {
      float a = ea[k];
      e0 = fmaf(a, We0[k], e0);
      e1 = fmaf(a, We1[k], e1);
    }
    float u0 = v0 + e0;
    float u1 = v1 + e1;
    u0 = fmaxf(u0, 0.2f * u0);          // leaky_relu
    u1 = fmaxf(u1, 0.2f * u1);

    float t0 = head_reduce32(u0 * att0);
    float t1 = head_reduce32(u1 * att1);

    // softmax without max-subtraction (|alpha| << 80, exp is safe; shift-invariant)
    float p0 = __expf(t0);
    float p1 = __expf(t1);
    S0 += p0;  S1 += p1;
    A0 = fmaf(p0, v0, A0);
    A1 = fmaf(p1, v1, A1);
  }

  float o0 = A0 / (S0 + 1e-16f) + bias_out[c0];
  float o1 = A1 / (S1 + 1e-16f) + bias_out[c1];
  float h0 = o0 > 0.f ? o0 : expm1f(o0);   // ELU
  float h1 = o1 > 0.f ? o1 : expm1f(o1);
  float r0 = h0 + x[(size_t)n * 128 + c0]; // residual
  float r1 = h1 + x[(size_t)n * 128 + c1];

  // LayerNorm over 128 channels, fully in-wave (2 ch/lane, 64 lanes)
  float s1 = r0 + r1;
  float s2 = r0 * r0 + r1 * r1;
  #pragma unroll
  for (int m = 1; m < 64; m <<= 1) {
    s1 += __shfl_xor(s1, m, 64);
    s2 += __shfl_xor(s2, m, 64);
  }
  float mean = s1 * (1.f / 128.f);
  float var  = s2 * (1.f / 128.f) - mean * mean;
  float rstd = rsqrtf(var + 1e-5f);
  out[(size_t)n * 128 + c0] = (r0 - mean) * rstd * gamma[c0] + beta[c0];
  out[(size_t)n * 128 + c1] = (r1 - mean) * rstd * gamma[c1] + beta[c1];
}

// ---------------- launch ----------------
extern "C" void kernel_launch(void* const* d_in, const int* in_sizes, int n_in,
                              void* d_out, int out_size, void* d_ws, size_t ws_size,
                              hipStream_t stream)
{
  const float* x         = (const float*)d_in[0];
  const int*   edge_idx  = (const int*)d_in[1];
  const float* edge_attr = (const float*)d_in[2];
  const float* Wl        = (const float*)d_in[3];
  const float* bl        = (const float*)d_in[4];
  const float* Wr        = (const float*)d_in[5];
  const float* br        = (const float*)d_in[6];
  const float* We        = (const float*)d_in[7];
  const float* att       = (const float*)d_in[8];
  const float* bias_out  = (const float*)d_in[9];
  const float* gamma     = (const float*)d_in[10];
  const float* beta      = (const float*)d_in[11];
  float* out = (float*)d_out;

  const int* src = edge_idx;        // edge_index[0]
  const int* dst = edge_idx + EE;   // edge_index[1]

  char* ws = (char*)d_ws;
  float* xl = (float*)ws;            ws += (size_t)NN * 128 * 4;   // 25.6 MB
  float* xr = (float*)ws;            ws += (size_t)NN * 128 * 4;   // 25.6 MB
  int* counts  = (int*)ws;           ws += (size_t)NN * 4;
  int* cursor  = (int*)ws;           ws += (size_t)NN * 4;
  int* row_ptr = (int*)ws;           ws += (size_t)(NN + 16) * 4;
  int2* csr = (int2*)ws;                                           // 8 MB

  hipMemsetAsync(counts, 0, (size_t)NN * 4, stream);

  lin_count_kernel<<<LIN_BLOCKS + CNT_BLOCKS, 256, 0, stream>>>(
      x, Wl, bl, Wr, br, xl, xr, dst, counts);
  scan_kernel<<<1, 1024, 0, stream>>>(counts, row_ptr, cursor);
  fill_kernel<<<CNT_BLOCKS, 256, 0, stream>>>(src, dst, cursor, csr);
  node_kernel<<<NN / 4, 256, 0, stream>>>(x, edge_attr, We, att, bias_out, gamma, beta,
                                          xl, xr, row_ptr, csr, out);
}

// Round 8
// 425.962 us; speedup vs baseline: 1.4617x; 1.3640x over previous
//
#include <hip/hip_runtime.h>
#include <math.h>

#define NN 50000
#define EE 1000000

#define LINB 782                        // ceil(50000/64) blocks of 64 rows
#define CNT_THREADS (EE / 4)            // 250000 int4 units
#define CNTB ((CNT_THREADS + 255) / 256)  // 977

typedef float f32x4 __attribute__((ext_vector_type(4)));
typedef __bf16 bf16x8 __attribute__((ext_vector_type(8)));

// ---------------- fused: bf16-MFMA lin GEMM (x@[Wl|Wr]+[bl|br]) + count/rank ----------------
__global__ __launch_bounds__(256) void lin_count_kernel(
    const float* __restrict__ x,
    const float* __restrict__ Wl, const float* __restrict__ bl,
    const float* __restrict__ Wr, const float* __restrict__ br,
    float* __restrict__ xl, float* __restrict__ xr,
    const int* __restrict__ dst, int* __restrict__ counts, int* __restrict__ rank)
{
  const int tid = threadIdx.x;

  if (blockIdx.x >= LINB) {
    // ---- degree count + per-edge rank (single atomic pass) ----
    int t = (blockIdx.x - LINB) * 256 + tid;
    if (t < CNT_THREADS) {
      int4 d4 = ((const int4*)dst)[t];
      int4 r4;
      r4.x = atomicAdd(&counts[d4.x], 1);
      r4.y = atomicAdd(&counts[d4.y], 1);
      r4.z = atomicAdd(&counts[d4.z], 1);
      r4.w = atomicAdd(&counts[d4.w], 1);
      ((int4*)rank)[t] = r4;
    }
    return;
  }

  // ---- MFMA GEMM: C[64 rows][256 cols], cols 0-127 -> xl (Wl), 128-255 -> xr (Wr) ----
  // W^T staged in LDS as bf16 [col][k], XOR-swizzled: byte ^= (col&7)<<4
  __shared__ __bf16 wt[256 * 128];   // 64 KB

  {
    const int c = tid;  // 0..255
    const float* __restrict__ Wsrc = (c < 128) ? (Wl + c) : (Wr + (c - 128));
    for (int k0 = 0; k0 < 128; k0 += 8) {
      bf16x8 v;
      #pragma unroll
      for (int j = 0; j < 8; ++j) v[j] = (__bf16)Wsrc[(size_t)(k0 + j) * 128];
      int byte = c * 256 + k0 * 2;
      byte ^= ((c & 7) << 4);
      *(bf16x8*)((char*)wt + byte) = v;
    }
  }
  __syncthreads();

  const int wave = tid >> 6;
  const int lane = tid & 63;
  const int l15  = lane & 15;
  const int lhi  = lane >> 4;   // 0..3

  const int row_a   = blockIdx.x * 64 + wave * 16 + l15;   // A-fragment row
  const int row_a_c = row_a < NN ? row_a : NN - 1;         // clamp (stores guarded)

  f32x4 acc[16];
  #pragma unroll
  for (int t = 0; t < 16; ++t) acc[t] = (f32x4)0.f;

  #pragma unroll
  for (int kk = 0; kk < 4; ++kk) {
    // A frag: x[row][kk*32 + lhi*8 .. +7], fp32 -> bf16
    const float* ap = x + (size_t)row_a_c * 128 + kk * 32 + lhi * 8;
    float4 a0 = *(const float4*)ap;
    float4 a1 = *(const float4*)(ap + 4);
    bf16x8 af;
    af[0] = (__bf16)a0.x; af[1] = (__bf16)a0.y; af[2] = (__bf16)a0.z; af[3] = (__bf16)a0.w;
    af[4] = (__bf16)a1.x; af[5] = (__bf16)a1.y; af[6] = (__bf16)a1.z; af[7] = (__bf16)a1.w;
    #pragma unroll
    for (int nt = 0; nt < 16; ++nt) {
      int col  = nt * 16 + l15;
      int byte = col * 256 + (kk * 32 + lhi * 8) * 2;
      byte ^= ((col & 7) << 4);
      bf16x8 bf = *(const bf16x8*)((const char*)wt + byte);
      acc[nt] = __builtin_amdgcn_mfma_f32_16x16x32_bf16(af, bf, acc[nt], 0, 0, 0);
    }
  }

  // epilogue: C layout col=lane&15, row=(lane>>4)*4+j  [m89-verified]
  const int row_base = blockIdx.x * 64 + wave * 16 + lhi * 4;
  #pragma unroll
  for (int nt = 0; nt < 16; ++nt) {
    int col = nt * 16 + l15;
    float bv = (col < 128) ? bl[col] : br[col - 128];
    float* dp = (col < 128) ? (xl + col) : (xr + (col - 128));
    #pragma unroll
    for (int j = 0; j < 4; ++j) {
      int r = row_base + j;
      if (r < NN) dp[(size_t)r * 128] = acc[nt][j] + bv;
    }
  }
}

// ---------------- scan: exclusive prefix over counts -> row_ptr ----------------
__global__ __launch_bounds__(1024) void scan_kernel(const int* __restrict__ counts,
                                                    int* __restrict__ row_ptr)
{
  __shared__ int s[1024];
  const int t = threadIdx.x;
  const int CH = (NN + 1023) / 1024;   // 49
  const int base = t * CH;
  int sum = 0;
  for (int j = 0; j < CH; ++j) {
    int idx = base + j;
    if (idx < NN) sum += counts[idx];
  }
  s[t] = sum;
  __syncthreads();
  for (int ofs = 1; ofs < 1024; ofs <<= 1) {
    int v = (t >= ofs) ? s[t - ofs] : 0;
    __syncthreads();
    s[t] += v;
    __syncthreads();
  }
  int run = s[t] - sum;
  for (int j = 0; j < CH; ++j) {
    int idx = base + j;
    if (idx < NN) { row_ptr[idx] = run; run += counts[idx]; }
  }
  if (t == 1023) row_ptr[NN] = s[1023];
}

// ---------------- fill: atomic-free placement via rank ----------------
__global__ __launch_bounds__(256) void fill_kernel(const int* __restrict__ src,
                                                   const int* __restrict__ dst,
                                                   const int* __restrict__ rank,
                                                   const int* __restrict__ row_ptr,
                                                   int2* __restrict__ csr)
{
  int t = blockIdx.x * 256 + threadIdx.x;
  if (t >= CNT_THREADS) return;
  int4 s4 = ((const int4*)src)[t];
  int4 d4 = ((const int4*)dst)[t];
  int4 r4 = ((const int4*)rank)[t];
  int e0 = t * 4;
  csr[row_ptr[d4.x] + r4.x] = make_int2(s4.x, e0 + 0);
  csr[row_ptr[d4.y] + r4.y] = make_int2(s4.y, e0 + 1);
  csr[row_ptr[d4.z] + r4.z] = make_int2(s4.z, e0 + 2);
  csr[row_ptr[d4.w] + r4.w] = make_int2(s4.w, e0 + 3);
}

// ---------------- fused per-node kernel ----------------
template<int CTRL>
__device__ __forceinline__ float dpp_add(float v)
{
  int y = __builtin_amdgcn_update_dpp(0, __float_as_int(v), CTRL, 0xF, 0xF, true);
  return v + __int_as_float(y);
}

__device__ __forceinline__ float head_reduce32(float v)
{
  v = dpp_add<0xB1>(v);    // quad_perm xor1
  v = dpp_add<0x4E>(v);    // quad_perm xor2
  v = dpp_add<0x141>(v);   // row_half_mirror
  v = dpp_add<0x140>(v);   // row_mirror
  int y = __builtin_amdgcn_ds_swizzle(__float_as_int(v), 0x401F); // xor16 within 32
  return v + __int_as_float(y);
}

__device__ __forceinline__ void edge_compute(
    float v0, float v1, float4 e0, float4 e1, float4 e2, float4 e3,
    const float* __restrict__ We0, const float* __restrict__ We1,
    float att0, float att1, float xr0, float xr1,
    float& S0, float& S1, float& A0, float& A1)
{
  float s0 = xr0, s1 = xr1;
  s0 = fmaf(e0.x, We0[0],  s0); s1 = fmaf(e0.x, We1[0],  s1);
  s0 = fmaf(e0.y, We0[1],  s0); s1 = fmaf(e0.y, We1[1],  s1);
  s0 = fmaf(e0.z, We0[2],  s0); s1 = fmaf(e0.z, We1[2],  s1);
  s0 = fmaf(e0.w, We0[3],  s0); s1 = fmaf(e0.w, We1[3],  s1);
  s0 = fmaf(e1.x, We0[4],  s0); s1 = fmaf(e1.x, We1[4],  s1);
  s0 = fmaf(e1.y, We0[5],  s0); s1 = fmaf(e1.y, We1[5],  s1);
  s0 = fmaf(e1.z, We0[6],  s0); s1 = fmaf(e1.z, We1[6],  s1);
  s0 = fmaf(e1.w, We0[7],  s0); s1 = fmaf(e1.w, We1[7],  s1);
  s0 = fmaf(e2.x, We0[8],  s0); s1 = fmaf(e2.x, We1[8],  s1);
  s0 = fmaf(e2.y, We0[9],  s0); s1 = fmaf(e2.y, We1[9],  s1);
  s0 = fmaf(e2.z, We0[10], s0); s1 = fmaf(e2.z, We1[10], s1);
  s0 = fmaf(e2.w, We0[11], s0); s1 = fmaf(e2.w, We1[11], s1);
  s0 = fmaf(e3.x, We0[12], s0); s1 = fmaf(e3.x, We1[12], s1);
  s0 = fmaf(e3.y, We0[13], s0); s1 = fmaf(e3.y, We1[13], s1);
  s0 = fmaf(e3.z, We0[14], s0); s1 = fmaf(e3.z, We1[14], s1);
  s0 = fmaf(e3.w, We0[15], s0); s1 = fmaf(e3.w, We1[15], s1);

  float u0 = v0 + s0;
  float u1 = v1 + s1;
  u0 = fmaxf(u0, 0.2f * u0);          // leaky_relu
  u1 = fmaxf(u1, 0.2f * u1);

  float t0 = head_reduce32(u0 * att0);
  float t1 = head_reduce32(u1 * att1);

  float p0 = __expf(t0);              // shift-free softmax (|alpha| small)
  float p1 = __expf(t1);
  S0 += p0;  S1 += p1;
  A0 = fmaf(p0, v0, A0);
  A1 = fmaf(p1, v1, A1);
}

__global__ __launch_bounds__(256) void node_kernel(
    const float* __restrict__ x,
    const float* __restrict__ edge_attr,
    const float* __restrict__ We,
    const float* __restrict__ att,
    const float* __restrict__ bias_out,
    const float* __restrict__ gamma,
    const float* __restrict__ beta,
    const float* __restrict__ xl,
    const float* __restrict__ xr,
    const int* __restrict__ row_ptr,
    const int2* __restrict__ csr,
    float* __restrict__ out)
{
  const int lane = threadIdx.x & 63;
  const int n = blockIdx.x * 4 + (threadIdx.x >> 6);
  const int c0 = lane;
  const int c1 = lane + 64;

  float We0[16], We1[16];
  #pragma unroll
  for (int k = 0; k < 16; ++k) { We0[k] = We[k * 128 + c0]; We1[k] = We[k * 128 + c1]; }
  const float att0 = att[c0], att1 = att[c1];
  const float xr0 = xr[(size_t)n * 128 + c0];
  const float xr1 = xr[(size_t)n * 128 + c1];

  const int i0 = __builtin_amdgcn_readfirstlane(row_ptr[n]);
  const int i1 = __builtin_amdgcn_readfirstlane(row_ptr[n + 1]);

  float S0a = 0.f, S1a = 0.f, A0a = 0.f, A1a = 0.f;
  float S0b = 0.f, S1b = 0.f, A0b = 0.f, A1b = 0.f;

  int i = i0;
  for (; i + 1 < i1; i += 2) {
    int2 sea = csr[i];
    int2 seb = csr[i + 1];
    int sa  = __builtin_amdgcn_readfirstlane(sea.x);
    int eia = __builtin_amdgcn_readfirstlane(sea.y);
    int sb  = __builtin_amdgcn_readfirstlane(seb.x);
    int eib = __builtin_amdgcn_readfirstlane(seb.y);

    const float* xla = xl + (size_t)sa * 128;
    const float* xlb = xl + (size_t)sb * 128;
    float va0 = xla[c0], va1 = xla[c1];
    float vb0 = xlb[c0], vb1 = xlb[c1];

    const float4* eaa = (const float4*)(edge_attr + (size_t)eia * 16);
    const float4* eab = (const float4*)(edge_attr + (size_t)eib * 16);
    float4 a0 = eaa[0], a1 = eaa[1], a2 = eaa[2], a3 = eaa[3];
    float4 b0 = eab[0], b1 = eab[1], b2 = eab[2], b3 = eab[3];

    edge_compute(va0, va1, a0, a1, a2, a3, We0, We1, att0, att1, xr0, xr1,
                 S0a, S1a, A0a, A1a);
    edge_compute(vb0, vb1, b0, b1, b2, b3, We0, We1, att0, att1, xr0, xr1,
                 S0b, S1b, A0b, A1b);
  }
  if (i < i1) {
    int2 se = csr[i];
    int s   = __builtin_amdgcn_readfirstlane(se.x);
    int eid = __builtin_amdgcn_readfirstlane(se.y);
    const float* xlp = xl + (size_t)s * 128;
    float v0 = xlp[c0], v1 = xlp[c1];
    const float4* ea4 = (const float4*)(edge_attr + (size_t)eid * 16);
    float4 a0 = ea4[0], a1 = ea4[1], a2 = ea4[2], a3 = ea4[3];
    edge_compute(v0, v1, a0, a1, a2, a3, We0, We1, att0, att1, xr0, xr1,
                 S0a, S1a, A0a, A1a);
  }

  float S0 = S0a + S0b, S1 = S1a + S1b;
  float A0 = A0a + A0b, A1 = A1a + A1b;

  float o0 = A0 / (S0 + 1e-16f) + bias_out[c0];
  float o1 = A1 / (S1 + 1e-16f) + bias_out[c1];
  float h0 = o0 > 0.f ? o0 : expm1f(o0);
  float h1 = o1 > 0.f ? o1 : expm1f(o1);
  float r0 = h0 + x[(size_t)n * 128 + c0];
  float r1 = h1 + x[(size_t)n * 128 + c1];

  // LayerNorm over 128 channels, in-wave (2 ch/lane)
  float s1 = r0 + r1;
  float s2 = r0 * r0 + r1 * r1;
  #pragma unroll
  for (int m = 1; m < 64; m <<= 1) {
    s1 += __shfl_xor(s1, m, 64);
    s2 += __shfl_xor(s2, m, 64);
  }
  float mean = s1 * (1.f / 128.f);
  float var  = s2 * (1.f / 128.f) - mean * mean;
  float rstd = rsqrtf(var + 1e-5f);
  out[(size_t)n * 128 + c0] = (r0 - mean) * rstd * gamma[c0] + beta[c0];
  out[(size_t)n * 128 + c1] = (r1 - mean) * rstd * gamma[c1] + beta[c1];
}

// ---------------- launch ----------------
extern "C" void kernel_launch(void* const* d_in, const int* in_sizes, int n_in,
                              void* d_out, int out_size, void* d_ws, size_t ws_size,
                              hipStream_t stream)
{
  const float* x         = (const float*)d_in[0];
  const int*   edge_idx  = (const int*)d_in[1];
  const float* edge_attr = (const float*)d_in[2];
  const float* Wl        = (const float*)d_in[3];
  const float* bl        = (const float*)d_in[4];
  const float* Wr        = (const float*)d_in[5];
  const float* br        = (const float*)d_in[6];
  const float* We        = (const float*)d_in[7];
  const float* att       = (const float*)d_in[8];
  const float* bias_out  = (const float*)d_in[9];
  const float* gamma     = (const float*)d_in[10];
  const float* beta      = (const float*)d_in[11];
  float* out = (float*)d_out;

  const int* src = edge_idx;        // edge_index[0]
  const int* dst = edge_idx + EE;   // edge_index[1]

  char* ws = (char*)d_ws;
  float* xl = (float*)ws;            ws += (size_t)NN * 128 * 4;   // 25.6 MB
  float* xr = (float*)ws;            ws += (size_t)NN * 128 * 4;   // 25.6 MB
  int* counts  = (int*)ws;           ws += (size_t)NN * 4;
  int* rank    = (int*)ws;           ws += (size_t)EE * 4;         // 4 MB
  int* row_ptr = (int*)ws;           ws += (size_t)(NN + 16) * 4;
  int2* csr = (int2*)ws;                                           // 8 MB

  hipMemsetAsync(counts, 0, (size_t)NN * 4, stream);

  lin_count_kernel<<<LINB + CNTB, 256, 0, stream>>>(
      x, Wl, bl, Wr, br, xl, xr, dst, counts, rank);
  scan_kernel<<<1, 1024, 0, stream>>>(counts, row_ptr);
  fill_kernel<<<CNTB, 256, 0, stream>>>(src, dst, rank, row_ptr, csr);
  node_kernel<<<NN / 4, 256, 0, stream>>>(x, edge_attr, We, att, bias_out, gamma, beta,
                                          xl, xr, row_ptr, csr, out);
}